// Round 7
// baseline (156.781 us; speedup 1.0000x reference)
//
#include <hip/hip_runtime.h>
#include <hip/hip_bf16.h>

// IterNorm: x(64,256,56,56) fp32 -> whiten per 64-ch group (4 groups) via
// Newton-Schulz (T=5), then *weight + bias.
//
// Pass 1:  k_gram   -- per-group gram + channel sums; partials coalesced in
//                      MFMA-native layout (no atomics). Distance-2 prefetch,
//                      double-buffered LDS. Also emits bf16(x) cache (XCACHE).
// Pass 1b: k_reduce -- sums 256 partials/element -> S1, S2 (deterministic).
// Pass 2:  k_ns     -- Sigma -> Sn -> 5 NS iters -> wm, beta = b - (wm@mu)*w
//                      (split hi/lo bf16 MFMA; lane-parallel trace).
// Pass 3:  k_apply  -- out = (wm @ x) * w + beta; operand-swapped MFMA,
//                      reads bf16(x) cache (no conversion, half the bytes),
//                      distance-2 prefetch, 2-buffer LDS, nt stores.

#define B_    64
#define C_    256
#define HW_   3136
#define G_    4
#define NC_   64
#define M_    (B_*HW_)          // 200704
#define EPS_  1e-5f
#define TIT_  5

#define NGB_  1024              // gram blocks (g, b, quad)
#define PBLK_ 256               // gram blocks per group

typedef __attribute__((ext_vector_type(8))) short  s16x8;
typedef __attribute__((ext_vector_type(4))) float  f32x4;

#define MFMA_(A,Bv,Cc) Cc = __builtin_amdgcn_mfma_f32_16x16x32_bf16(A, Bv, Cc, 0, 0, 0)

__device__ __forceinline__ unsigned short f2bf(float f){
  union{ float f; unsigned int u; } c; c.f = f;
  unsigned int u = c.u;
  u = u + 0x7FFFu + ((u >> 16) & 1u);
  return (unsigned short)(u >> 16);
}
__device__ __forceinline__ float bf2f(unsigned short h){
  union{ unsigned int u; float f; } c; c.u = ((unsigned int)h) << 16;
  return c.f;
}
// XOR swizzle for [row][64] bf16 tiles read column-wise (gram / NS).
__device__ __forceinline__ int swz(int off, int row){
  return off ^ ((row & 7) << 4) ^ (((row >> 3) & 3) << 5);
}
__device__ __forceinline__ s16x8 ld_frag(const unsigned short* base, int row, int kbyte){
  return *(const s16x8*)((const char*)base + swz(row*128 + kbyte, row));
}
__device__ __forceinline__ void st_h(unsigned short* base, int row, int col, unsigned short v){
  *(unsigned short*)((char*)base + swz(row*128 + col*2, row)) = v;
}
__device__ __forceinline__ unsigned short ld_h(const unsigned short* base, int row, int col){
  return *(const unsigned short*)((const char*)base + swz(row*128 + col*2, row));
}

// ---------------- Pass 1: gram + sums ----------------
template<bool ATOMIC, bool XCACHE>
__global__ __launch_bounds__(256) void k_gram(const float* __restrict__ x,
                                              float* __restrict__ S1,
                                              float* __restrict__ S2,
                                              float* __restrict__ partS2,
                                              float* __restrict__ partS1,
                                              unsigned short* __restrict__ xb){
  __shared__ __align__(16) unsigned short tile[2][64*64];
  const int tid  = threadIdx.x;
  const int lane = tid & 63, wave = tid >> 6;
  const int bx   = blockIdx.x;
  const int g = bx >> 8, sub = bx & 255, b = sub >> 2, quad = sub & 3;
  const int ck0 = (quad*49) >> 2, ck1 = ((quad+1)*49) >> 2;
  const int nck = ck1 - ck0;
  const size_t base = ((size_t)b*C_ + (size_t)g*NC_) * HW_;
  const float* xg = x + base;
  unsigned short* xbg = XCACHE ? (xb + base) : nullptr;
  const int chb = (tid >> 4) * 4;       // this thread's 4 channels: chb+q
  const int posoff = (tid & 15) * 4;
  const int wrow = (wave >> 1) * 32, wcol = (wave & 1) * 32;
  float s1a[4] = {0.f,0.f,0.f,0.f};
  f32x4 acc[2][2] = {};
  float v[4][4];

  auto load_c = [&](int ck){
    #pragma unroll
    for(int q = 0; q < 4; ++q){
      const float4 t = *(const float4*)(xg + (size_t)(chb+q)*HW_ + ck*64 + posoff);
      v[q][0]=t.x; v[q][1]=t.y; v[q][2]=t.z; v[q][3]=t.w;
    }
  };
  auto write_c = [&](unsigned short* tl, int ck){
    #pragma unroll
    for(int q = 0; q < 4; ++q){
      s1a[q] += v[q][0]+v[q][1]+v[q][2]+v[q][3];
      const int ch = chb + q;
      const unsigned long long pk =
            (unsigned long long)f2bf(v[q][0])
          | ((unsigned long long)f2bf(v[q][1]) << 16)
          | ((unsigned long long)f2bf(v[q][2]) << 32)
          | ((unsigned long long)f2bf(v[q][3]) << 48);
      *(unsigned long long*)((char*)tl + swz(ch*128 + posoff*2, ch)) = pk;
      if(XCACHE)
        *(unsigned long long*)(xbg + (size_t)ch*HW_ + ck*64 + posoff) = pk;
    }
  };
  auto comp = [&](const unsigned short* tl){
    #pragma unroll
    for(int ks = 0; ks < 2; ++ks){
      const int kbyte = ks*64 + (lane >> 4) * 16;
      s16x8 a0 = ld_frag(tl, wrow +      (lane & 15), kbyte);
      s16x8 a1 = ld_frag(tl, wrow + 16 + (lane & 15), kbyte);
      s16x8 b0 = ld_frag(tl, wcol +      (lane & 15), kbyte);
      s16x8 b1 = ld_frag(tl, wcol + 16 + (lane & 15), kbyte);
      MFMA_(a0, b0, acc[0][0]);
      MFMA_(a0, b1, acc[0][1]);
      MFMA_(a1, b0, acc[1][0]);
      MFMA_(a1, b1, acc[1][1]);
    }
  };

  // distance-2 prefetch, 2 LDS buffers: at iter i publish chunk i+1
  // (written buffer was last *read* at iter i-1, behind the barrier),
  // issue loads for i+2, compute chunk i.
  load_c(ck0);
  write_c(tile[0], ck0);
  if(nck > 1) load_c(ck0 + 1);
  __syncthreads();
  for(int i = 0; i < nck; ++i){
    if(i + 1 < nck) write_c(tile[(i+1)&1], ck0 + i + 1);
    if(i + 2 < nck) load_c(ck0 + i + 2);
    comp(tile[i&1]);
    __syncthreads();
  }

  if(ATOMIC){
    float* S2g = S2 + g * (NC_*NC_);
    #pragma unroll
    for(int i = 0; i < 2; ++i)
    #pragma unroll
    for(int j = 0; j < 2; ++j)
    #pragma unroll
    for(int r = 0; r < 4; ++r){
      const int d = wrow + 16*i + (lane >> 4)*4 + r;
      const int e = wcol + 16*j + (lane & 15);
      atomicAdd(&S2g[d*NC_ + e], acc[i][j][r]);
    }
  }else{
    // MFMA-native layout: fully coalesced float4 stream, no remap here.
    float* p2 = partS2 + (size_t)bx*4096 + tid*16;
    #pragma unroll
    for(int i = 0; i < 2; ++i)
    #pragma unroll
    for(int j = 0; j < 2; ++j)
      *(f32x4*)(p2 + (i*2+j)*4) = acc[i][j];
  }
  #pragma unroll
  for(int q = 0; q < 4; ++q){
    float s = s1a[q];
    #pragma unroll
    for(int m2 = 1; m2 < 16; m2 <<= 1) s += __shfl_xor(s, m2, 64);
    if((lane & 15) == 0){
      if(ATOMIC) atomicAdd(&S1[g*NC_ + chb + q], s);
      else       partS1[(size_t)bx*64 + chb + q] = s;
    }
  }
}

// ---------------- Pass 1b: reduce partials ----------------
// 260 blocks: 0..255 handle S2 (4 threads/element x 64 partials each),
// 256..259 handle S1 (one group per block). Deterministic order.
__global__ __launch_bounds__(256) void k_reduce(const float* __restrict__ partS2,
                                                const float* __restrict__ partS1,
                                                float* __restrict__ S1,
                                                float* __restrict__ S2){
  const int bid = blockIdx.x, tid = threadIdx.x;
  const int sub = tid & 3;
  if(bid < 256){
    const int flat = (bid*256 + tid) >> 2;   // element 0..16383
    const int g = flat >> 12, t = flat & 4095;
    const float* p = partS2 + ((size_t)(g*PBLK_ + sub*64))*4096 + t;
    float s = 0.f;
    for(int jb = 0; jb < 64; ++jb) s += p[(size_t)jb*4096];
    s += __shfl_xor(s, 1, 64);
    s += __shfl_xor(s, 2, 64);
    if(sub == 0){
      // invert MFMA-native layout -> (d,e)
      const int tt = t >> 4, q = (t >> 2) & 3, r = t & 3;
      const int wave = tt >> 6, lane = tt & 63;
      const int d = (wave >> 1)*32 + ((q >> 1) << 4) + ((lane >> 4) << 2) + r;
      const int e = (wave &  1)*32 + ((q &  1) << 4) + (lane & 15);
      S2[g*4096 + d*64 + e] = s;
    }
  }else{
    const int g = bid - 256, ch = tid >> 2;
    const float* p = partS1 + ((size_t)(g*PBLK_ + sub*64))*64 + ch;
    float s = 0.f;
    for(int jb = 0; jb < 64; ++jb) s += p[(size_t)jb*64];
    s += __shfl_xor(s, 1, 64);
    s += __shfl_xor(s, 2, 64);
    if(sub == 0) S1[g*NC_ + ch] = s;
  }
}

// ---------------- Pass 2: Newton-Schulz ----------------
__device__ __forceinline__ void mm_core(f32x4 acc[2][2],
    const unsigned short* Ah, const unsigned short* Al,
    const unsigned short* Bh, const unsigned short* Bl,
    int lane, int wrow, int wcol){
  #pragma unroll
  for(int ks = 0; ks < 2; ++ks){
    const int kbyte = ks*64 + (lane >> 4) * 16;
    s16x8 ah0 = ld_frag(Ah, wrow +      (lane & 15), kbyte);
    s16x8 ah1 = ld_frag(Ah, wrow + 16 + (lane & 15), kbyte);
    s16x8 al0 = ld_frag(Al, wrow +      (lane & 15), kbyte);
    s16x8 al1 = ld_frag(Al, wrow + 16 + (lane & 15), kbyte);
    s16x8 bh0 = ld_frag(Bh, wcol +      (lane & 15), kbyte);
    s16x8 bh1 = ld_frag(Bh, wcol + 16 + (lane & 15), kbyte);
    s16x8 bl0 = ld_frag(Bl, wcol +      (lane & 15), kbyte);
    s16x8 bl1 = ld_frag(Bl, wcol + 16 + (lane & 15), kbyte);
    MFMA_(ah0, bh0, acc[0][0]); MFMA_(ah0, bl0, acc[0][0]); MFMA_(al0, bh0, acc[0][0]);
    MFMA_(ah0, bh1, acc[0][1]); MFMA_(ah0, bl1, acc[0][1]); MFMA_(al0, bh1, acc[0][1]);
    MFMA_(ah1, bh0, acc[1][0]); MFMA_(ah1, bl0, acc[1][0]); MFMA_(al1, bh0, acc[1][0]);
    MFMA_(ah1, bh1, acc[1][1]); MFMA_(ah1, bl1, acc[1][1]); MFMA_(al1, bh1, acc[1][1]);
  }
}

__device__ __forceinline__ void mm64(unsigned short* dH, unsigned short* dL,
    const unsigned short* Ah, const unsigned short* Al,
    const unsigned short* Bh, const unsigned short* Bl,
    int lane, int wrow, int wcol){
  f32x4 acc[2][2] = {};
  mm_core(acc, Ah, Al, Bh, Bl, lane, wrow, wcol);
  #pragma unroll
  for(int i = 0; i < 2; ++i)
  #pragma unroll
  for(int j = 0; j < 2; ++j)
  #pragma unroll
  for(int r = 0; r < 4; ++r){
    const int d = wrow + 16*i + (lane >> 4)*4 + r;
    const int e = wcol + 16*j + (lane & 15);
    const float v = acc[i][j][r];
    const unsigned short h = f2bf(v);
    st_h(dH, d, e, h);
    st_h(dL, d, e, f2bf(v - bf2f(h)));
  }
}

__device__ __forceinline__ void ns_update(unsigned short* dH, unsigned short* dL,
    const unsigned short* Zh, const unsigned short* Zl,
    const unsigned short* Snh, const unsigned short* Snl,
    const unsigned short* pH, const unsigned short* pL,
    int lane, int wrow, int wcol){
  f32x4 acc[2][2] = {};
  mm_core(acc, Zh, Zl, Snh, Snl, lane, wrow, wcol);
  #pragma unroll
  for(int i = 0; i < 2; ++i)
  #pragma unroll
  for(int j = 0; j < 2; ++j)
  #pragma unroll
  for(int r = 0; r < 4; ++r){
    const int d = wrow + 16*i + (lane >> 4)*4 + r;
    const int e = wcol + 16*j + (lane & 15);
    const float pv = bf2f(ld_h(pH, d, e)) + bf2f(ld_h(pL, d, e));
    const float v = 1.5f*pv - 0.5f*acc[i][j][r];
    const unsigned short h = f2bf(v);
    st_h(dH, d, e, h);
    st_h(dL, d, e, f2bf(v - bf2f(h)));
  }
}

__global__ __launch_bounds__(256) void k_ns(const float* __restrict__ S1,
                                            const float* __restrict__ S2,
                                            const float* __restrict__ weight,
                                            const float* __restrict__ bias,
                                            float* __restrict__ wm,
                                            float* __restrict__ beta){
  __shared__ __align__(16) unsigned short smem[8*4096];   // 64 KiB exactly
  unsigned short* Snh = smem;
  unsigned short* Snl = smem + 1*4096;
  unsigned short* Xh  = smem + 2*4096;
  unsigned short* Xl  = smem + 3*4096;
  unsigned short* Yh  = smem + 4*4096;
  unsigned short* Yl  = smem + 5*4096;
  unsigned short* Zh  = smem + 6*4096;
  unsigned short* Zl  = smem + 7*4096;
  const int g = blockIdx.x, tid = threadIdx.x;
  const int lane = tid & 63, wave = tid >> 6;
  const float* S1g = S1 + g*NC_;
  const float* S2g = S2 + g*NC_*NC_;
  const float invm = 1.0f / (float)M_;

  // trace of Sigma: lane-parallel (1 diag elem / lane) + butterfly reduce
  float term;
  {
    const float mui = S1g[lane] * invm;
    term = S2g[lane*NC_ + lane]*invm - mui*mui + EPS_;
    #pragma unroll
    for(int m2 = 1; m2 < 64; m2 <<= 1) term += __shfl_xor(term, m2, 64);
  }
  const float rTr  = 1.0f / term;
  const float srtr = sqrtf(rTr);

  {
    const int d  = tid >> 2;
    const int e0 = (tid & 3) * 16;
    const float mud = S1g[d] * invm;
    for(int k = 0; k < 16; ++k){
      const int e = e0 + k;
      const float mue = S1g[e] * invm;
      const float s = (S2g[d*NC_ + e]*invm - mud*mue + ((d==e)?EPS_:0.f)) * rTr;
      const unsigned short h = f2bf(s);
      st_h(Snh, d, e, h);
      st_h(Snl, d, e, f2bf(s - bf2f(h)));
      st_h(Xh,  d, e, (d==e)?(unsigned short)0x3F80:(unsigned short)0);
      st_h(Xl,  d, e, (unsigned short)0);
    }
  }
  __syncthreads();

  unsigned short *pH = Xh, *pL = Xl, *qH = Yh, *qL = Yl;
  const int wrow = (wave >> 1)*32, wcol = (wave & 1)*32;
  for(int it = 0; it < TIT_; ++it){
    mm64(qH, qL, pH, pL, pH, pL, lane, wrow, wcol);     // T1 = P*P
    __syncthreads();
    mm64(Zh, Zl, qH, qL, pH, pL, lane, wrow, wcol);     // T2 = T1*P
    __syncthreads();
    ns_update(qH, qL, Zh, Zl, Snh, Snl, pH, pL, lane, wrow, wcol); // P' into q
    __syncthreads();
    unsigned short* t;
    t = pH; pH = qH; qH = t;
    t = pL; pL = qL; qL = t;
  }

  // wm = P*sqrt(rTr); beta = bias - weight * (wm @ mu)
  float* wmg = wm + g*NC_*NC_;
  const int d  = tid >> 2;
  const int e0 = (tid & 3) * 16;
  float rs = 0.f;
  for(int k = 0; k < 16; ++k){
    const int e = e0 + k;
    const float wv = (bf2f(ld_h(pH, d, e)) + bf2f(ld_h(pL, d, e))) * srtr;
    wmg[d*NC_ + e] = wv;
    rs += wv * (S1g[e] * invm);
  }
  rs += __shfl_xor(rs, 1, 64);
  rs += __shfl_xor(rs, 2, 64);
  if((tid & 3) == 0)
    beta[g*NC_ + d] = bias[g*NC_ + d] - weight[g*NC_ + d] * rs;
}

// ---------------- Pass 3: apply ----------------
template<bool XCACHE>
__global__ __launch_bounds__(256) void k_apply(const float* __restrict__ x,
                                               const unsigned short* __restrict__ xb,
                                               const float* __restrict__ wm,
                                               const float* __restrict__ beta,
                                               const float* __restrict__ weight,
                                               float* __restrict__ out){
  // transposed tile: [pos][ch], rows 128B, byte ^= (pos&7)<<4
  __shared__ __align__(16) unsigned short tileT[2][64*64];
  const int tid  = threadIdx.x;
  const int lane = tid & 63, wave = tid >> 6;
  const int bx   = blockIdx.x;
  const int g = bx >> 9, sub = bx & 511, b = sub >> 3, oct = sub & 7;
  const int ck0 = (oct*49) >> 3, ck1 = ((oct+1)*49) >> 3;
  const int nck = ck1 - ck0;
  const size_t base = ((size_t)b*C_ + (size_t)g*NC_) * HW_;
  const float*          xg  = x  + base;
  const unsigned short* xg16 = XCACHE ? (xb + base) : nullptr;
  float*                og  = out + base;
  const int chb = (tid >> 4) * 4;
  const int posoff = (tid & 15) * 4;

  // wm fragments (hi/lo) in registers; wm symmetric, used as B operand.
  const float* wmg = wm + g*NC_*NC_;
  const int arow = wave*16 + (lane & 15);   // this lane's output channel
  s16x8 ah[2], al[2];
  #pragma unroll
  for(int ks = 0; ks < 2; ++ks){
    const int kc = ks*32 + (lane >> 4)*8;
    const float* p = wmg + arow*NC_ + kc;
    #pragma unroll
    for(int j = 0; j < 8; ++j){
      const float w = p[j];
      const unsigned short h = f2bf(w);
      ah[ks][j] = (short)h;
      al[ks][j] = (short)f2bf(w - bf2f(h));
    }
  }
  const int cl = wave*16 + (lane & 15);     // output channel (local)
  const float wt = weight[g*NC_ + cl];
  const float bt = beta  [g*NC_ + cl];

  float v[4][4];                            // fp32 path only
  unsigned long long pkv[4];                // bf16-cache path
  auto load_c = [&](int ck){
    #pragma unroll
    for(int q = 0; q < 4; ++q){
      if(XCACHE){
        pkv[q] = *(const unsigned long long*)(xg16 + (size_t)(chb+q)*HW_ + ck*64 + posoff);
      }else{
        const float4 t = *(const float4*)(xg + (size_t)(chb+q)*HW_ + ck*64 + posoff);
        v[q][0]=t.x; v[q][1]=t.y; v[q][2]=t.z; v[q][3]=t.w;
      }
    }
  };
  auto write_c = [&](unsigned short* tl){
    if(XCACHE){
      // pkv[q] = 4 bf16 positions for channel chb+q; transpose via per-element
      // u16 stores into swizzled [pos][ch] tile (same addresses as fp32 path).
      #pragma unroll
      for(int r = 0; r < 4; ++r){
        const int p = posoff + r;
        const unsigned long long pk =
              ((pkv[0] >> (16*r)) & 0xFFFFull)
            | (((pkv[1] >> (16*r)) & 0xFFFFull) << 16)
            | (((pkv[2] >> (16*r)) & 0xFFFFull) << 32)
            | (((pkv[3] >> (16*r)) & 0xFFFFull) << 48);
        *(unsigned long long*)((char*)tl + p*128 + ((chb*2) ^ ((p & 7) << 4))) = pk;
      }
    }else{
      #pragma unroll
      for(int r = 0; r < 4; ++r){
        const int p = posoff + r;
        const unsigned long long pk =
              (unsigned long long)f2bf(v[0][r])
            | ((unsigned long long)f2bf(v[1][r]) << 16)
            | ((unsigned long long)f2bf(v[2][r]) << 32)
            | ((unsigned long long)f2bf(v[3][r]) << 48);
        *(unsigned long long*)((char*)tl + p*128 + ((chb*2) ^ ((p & 7) << 4))) = pk;
      }
    }
  };
  auto comp = [&](const unsigned short* tl, int p0){
    #pragma unroll
    for(int tn = 0; tn < 4; ++tn){
      f32x4 acc = {0.f,0.f,0.f,0.f};
      const int pos = tn*16 + (lane & 15);   // A row = position
      #pragma unroll
      for(int ks = 0; ks < 2; ++ks){
        const int cb = (ks*64 + (lane >> 4)*16) ^ ((pos & 7) << 4);
        const s16x8 afr = *(const s16x8*)((const char*)tl + pos*128 + cb);
        MFMA_(afr, ah[ks], acc);             // D[pos][ch_out]
        MFMA_(afr, al[ks], acc);
      }
      const int pr = p0 + tn*16 + ((lane >> 4) << 2);  // 4 consecutive positions
      f32x4 o;
      o[0] = acc[0]*wt + bt;
      o[1] = acc[1]*wt + bt;
      o[2] = acc[2]*wt + bt;
      o[3] = acc[3]*wt + bt;
      __builtin_nontemporal_store(o, (f32x4*)(og + (size_t)cl*HW_ + pr));
    }
  };

  // distance-2 prefetch, 2 LDS buffers (same schedule as k_gram)
  load_c(ck0);
  write_c(tileT[0]);
  if(nck > 1) load_c(ck0 + 1);
  __syncthreads();
  for(int i = 0; i < nck; ++i){
    if(i + 1 < nck) write_c(tileT[(i+1)&1]);
    if(i + 2 < nck) load_c(ck0 + i + 2);
    comp(tileT[i&1], (ck0 + i)*64);
    __syncthreads();
  }
}

extern "C" void kernel_launch(void* const* d_in, const int* in_sizes, int n_in,
                              void* d_out, int out_size, void* d_ws, size_t ws_size,
                              hipStream_t stream){
  (void)in_sizes; (void)n_in; (void)out_size;
  const float* x  = (const float*)d_in[0];
  const float* w  = (const float*)d_in[1];
  const float* bs = (const float*)d_in[2];
  float* out  = (float*)d_out;
  float* S1   = (float*)d_ws;                // 256
  float* S2   = S1 + 256;                    // 4*4096
  float* beta = S2 + G_*NC_*NC_;             // 256
  float* wm   = beta + 256;                  // 4*4096
  float* p2   = wm + G_*NC_*NC_;             // NGB_*4096
  float* p1   = p2 + (size_t)NGB_*4096;      // NGB_*64
  unsigned short* xb = (unsigned short*)(p1 + (size_t)NGB_*64);  // B_*C_*HW_ bf16
  const size_t need_nox = ((size_t)(256 + G_*4096 + 256 + G_*4096)
                           + (size_t)NGB_*4096 + (size_t)NGB_*64) * sizeof(float);
  const size_t need_x   = need_nox + (size_t)B_*C_*HW_*sizeof(unsigned short);
  if(ws_size >= need_x){
    k_gram<false,true><<<NGB_, 256, 0, stream>>>(x, S1, S2, p2, p1, xb);
    k_reduce<<<260, 256, 0, stream>>>(p2, p1, S1, S2);
    k_ns   <<<G_,   256, 0, stream>>>(S1, S2, w, bs, wm, beta);
    k_apply<true><<<2048, 256, 0, stream>>>(x, xb, wm, beta, w, out);
  }else if(ws_size >= need_nox){
    k_gram<false,false><<<NGB_, 256, 0, stream>>>(x, S1, S2, p2, p1, nullptr);
    k_reduce<<<260, 256, 0, stream>>>(p2, p1, S1, S2);
    k_ns   <<<G_,   256, 0, stream>>>(S1, S2, w, bs, wm, beta);
    k_apply<false><<<2048, 256, 0, stream>>>(x, nullptr, wm, beta, w, out);
  }else{
    hipError_t _e = hipMemsetAsync(d_ws, 0, (256 + G_*NC_*NC_)*sizeof(float), stream);
    (void)_e;
    k_gram<true,false><<<NGB_, 256, 0, stream>>>(x, S1, S2, p2, p1, nullptr);
    k_ns   <<<G_,   256, 0, stream>>>(S1, S2, w, bs, wm, beta);
    k_apply<false><<<2048, 256, 0, stream>>>(x, nullptr, wm, beta, w, out);
  }
}

// Round 8
// 150.405 us; speedup vs baseline: 1.0424x; 1.0424x over previous
//
#include <hip/hip_runtime.h>
#include <hip/hip_bf16.h>

// IterNorm: x(64,256,56,56) fp32 -> whiten per 64-ch group (4 groups) via
// Newton-Schulz (T=5), then *weight + bias.
//
// Pass 1:  k_gram   -- per-group gram + channel sums; partials coalesced in
//                      MFMA-native layout (no atomics). Distance-2 prefetch,
//                      double-buffered LDS, raw-barrier (loads/stores stay
//                      in flight across workgroup barriers).
// Pass 1b: k_reduce -- sums 256 partials/element -> S1, S2 (deterministic).
// Pass 2:  k_ns     -- Sigma -> Sn -> 5 NS iters -> wm, beta = b - (wm@mu)*w
//                      (split hi/lo bf16 MFMA; lane-parallel trace).
// Pass 3:  k_apply  -- out = (wm @ x) * w + beta; operand-swapped MFMA,
//                      distance-2 prefetch, 2-buffer LDS, nt stores that are
//                      never force-drained (raw barrier, not __syncthreads).

#define B_    64
#define C_    256
#define HW_   3136
#define G_    4
#define NC_   64
#define M_    (B_*HW_)          // 200704
#define EPS_  1e-5f
#define TIT_  5

#define NGB_  1024              // gram blocks (g, b, quad)
#define PBLK_ 256               // gram blocks per group

typedef __attribute__((ext_vector_type(8))) short  s16x8;
typedef __attribute__((ext_vector_type(4))) float  f32x4;

#define MFMA_(A,Bv,Cc) Cc = __builtin_amdgcn_mfma_f32_16x16x32_bf16(A, Bv, Cc, 0, 0, 0)

// Workgroup barrier WITHOUT vmcnt(0) drain: LDS writes are made visible
// (lgkmcnt(0)) but global loads (prefetch) and nt stores stay in flight.
// The compiler still inserts precise vmcnt(N) waits where load data is used.
__device__ __forceinline__ void wg_barrier(){
  asm volatile("s_waitcnt lgkmcnt(0)" ::: "memory");
  __builtin_amdgcn_s_barrier();
}

__device__ __forceinline__ unsigned short f2bf(float f){
  union{ float f; unsigned int u; } c; c.f = f;
  unsigned int u = c.u;
  u = u + 0x7FFFu + ((u >> 16) & 1u);
  return (unsigned short)(u >> 16);
}
__device__ __forceinline__ float bf2f(unsigned short h){
  union{ unsigned int u; float f; } c; c.u = ((unsigned int)h) << 16;
  return c.f;
}
// XOR swizzle for [row][64] bf16 tiles read column-wise (gram / NS).
__device__ __forceinline__ int swz(int off, int row){
  return off ^ ((row & 7) << 4) ^ (((row >> 3) & 3) << 5);
}
__device__ __forceinline__ s16x8 ld_frag(const unsigned short* base, int row, int kbyte){
  return *(const s16x8*)((const char*)base + swz(row*128 + kbyte, row));
}
__device__ __forceinline__ void st_h(unsigned short* base, int row, int col, unsigned short v){
  *(unsigned short*)((char*)base + swz(row*128 + col*2, row)) = v;
}
__device__ __forceinline__ unsigned short ld_h(const unsigned short* base, int row, int col){
  return *(const unsigned short*)((const char*)base + swz(row*128 + col*2, row));
}

// ---------------- Pass 1: gram + sums ----------------
template<bool ATOMIC>
__global__ __launch_bounds__(256) void k_gram(const float* __restrict__ x,
                                              float* __restrict__ S1,
                                              float* __restrict__ S2,
                                              float* __restrict__ partS2,
                                              float* __restrict__ partS1){
  __shared__ __align__(16) unsigned short tile[2][64*64];
  const int tid  = threadIdx.x;
  const int lane = tid & 63, wave = tid >> 6;
  const int bx   = blockIdx.x;
  const int g = bx >> 8, sub = bx & 255, b = sub >> 2, quad = sub & 3;
  const int ck0 = (quad*49) >> 2, ck1 = ((quad+1)*49) >> 2;
  const int nck = ck1 - ck0;
  const float* xg = x + ((size_t)b*C_ + (size_t)g*NC_) * HW_;
  const int chb = (tid >> 4) * 4;       // this thread's 4 channels: chb+q
  const int posoff = (tid & 15) * 4;
  const int wrow = (wave >> 1) * 32, wcol = (wave & 1) * 32;
  float s1a[4] = {0.f,0.f,0.f,0.f};
  f32x4 acc[2][2] = {};
  float v[4][4];

  auto load_c = [&](int ck){
    #pragma unroll
    for(int q = 0; q < 4; ++q){
      const float4 t = *(const float4*)(xg + (size_t)(chb+q)*HW_ + ck*64 + posoff);
      v[q][0]=t.x; v[q][1]=t.y; v[q][2]=t.z; v[q][3]=t.w;
    }
  };
  auto write_c = [&](unsigned short* tl){
    #pragma unroll
    for(int q = 0; q < 4; ++q){
      s1a[q] += v[q][0]+v[q][1]+v[q][2]+v[q][3];
      const int ch = chb + q;
      const unsigned long long pk =
            (unsigned long long)f2bf(v[q][0])
          | ((unsigned long long)f2bf(v[q][1]) << 16)
          | ((unsigned long long)f2bf(v[q][2]) << 32)
          | ((unsigned long long)f2bf(v[q][3]) << 48);
      *(unsigned long long*)((char*)tl + swz(ch*128 + posoff*2, ch)) = pk;
    }
  };
  auto comp = [&](const unsigned short* tl){
    #pragma unroll
    for(int ks = 0; ks < 2; ++ks){
      const int kbyte = ks*64 + (lane >> 4) * 16;
      s16x8 a0 = ld_frag(tl, wrow +      (lane & 15), kbyte);
      s16x8 a1 = ld_frag(tl, wrow + 16 + (lane & 15), kbyte);
      s16x8 b0 = ld_frag(tl, wcol +      (lane & 15), kbyte);
      s16x8 b1 = ld_frag(tl, wcol + 16 + (lane & 15), kbyte);
      MFMA_(a0, b0, acc[0][0]);
      MFMA_(a0, b1, acc[0][1]);
      MFMA_(a1, b0, acc[1][0]);
      MFMA_(a1, b1, acc[1][1]);
    }
  };

  // distance-2 prefetch, 2 LDS buffers: at iter i publish chunk i+1
  // (the written buffer was last *read* at iter i-1, behind the barrier),
  // issue loads for i+2, compute chunk i. Raw barrier keeps loads in flight.
  load_c(ck0);
  write_c(tile[0]);
  if(nck > 1) load_c(ck0 + 1);
  wg_barrier();
  for(int i = 0; i < nck; ++i){
    if(i + 1 < nck) write_c(tile[(i+1)&1]);
    if(i + 2 < nck) load_c(ck0 + i + 2);
    comp(tile[i&1]);
    wg_barrier();
  }

  if(ATOMIC){
    float* S2g = S2 + g * (NC_*NC_);
    #pragma unroll
    for(int i = 0; i < 2; ++i)
    #pragma unroll
    for(int j = 0; j < 2; ++j)
    #pragma unroll
    for(int r = 0; r < 4; ++r){
      const int d = wrow + 16*i + (lane >> 4)*4 + r;
      const int e = wcol + 16*j + (lane & 15);
      atomicAdd(&S2g[d*NC_ + e], acc[i][j][r]);
    }
  }else{
    // MFMA-native layout: fully coalesced float4 stream, no remap here.
    float* p2 = partS2 + (size_t)bx*4096 + tid*16;
    #pragma unroll
    for(int i = 0; i < 2; ++i)
    #pragma unroll
    for(int j = 0; j < 2; ++j)
      *(f32x4*)(p2 + (i*2+j)*4) = acc[i][j];
  }
  #pragma unroll
  for(int q = 0; q < 4; ++q){
    float s = s1a[q];
    #pragma unroll
    for(int m2 = 1; m2 < 16; m2 <<= 1) s += __shfl_xor(s, m2, 64);
    if((lane & 15) == 0){
      if(ATOMIC) atomicAdd(&S1[g*NC_ + chb + q], s);
      else       partS1[(size_t)bx*64 + chb + q] = s;
    }
  }
}

// ---------------- Pass 1b: reduce partials ----------------
// 260 blocks: 0..255 handle S2 (4 threads/element x 64 partials each),
// 256..259 handle S1 (one group per block). Deterministic order.
__global__ __launch_bounds__(256) void k_reduce(const float* __restrict__ partS2,
                                                const float* __restrict__ partS1,
                                                float* __restrict__ S1,
                                                float* __restrict__ S2){
  const int bid = blockIdx.x, tid = threadIdx.x;
  const int sub = tid & 3;
  if(bid < 256){
    const int flat = (bid*256 + tid) >> 2;   // element 0..16383
    const int g = flat >> 12, t = flat & 4095;
    const float* p = partS2 + ((size_t)(g*PBLK_ + sub*64))*4096 + t;
    float s = 0.f;
    for(int jb = 0; jb < 64; ++jb) s += p[(size_t)jb*4096];
    s += __shfl_xor(s, 1, 64);
    s += __shfl_xor(s, 2, 64);
    if(sub == 0){
      // invert MFMA-native layout -> (d,e)
      const int tt = t >> 4, q = (t >> 2) & 3, r = t & 3;
      const int wave = tt >> 6, lane = tt & 63;
      const int d = (wave >> 1)*32 + ((q >> 1) << 4) + ((lane >> 4) << 2) + r;
      const int e = (wave &  1)*32 + ((q &  1) << 4) + (lane & 15);
      S2[g*4096 + d*64 + e] = s;
    }
  }else{
    const int g = bid - 256, ch = tid >> 2;
    const float* p = partS1 + ((size_t)(g*PBLK_ + sub*64))*64 + ch;
    float s = 0.f;
    for(int jb = 0; jb < 64; ++jb) s += p[(size_t)jb*64];
    s += __shfl_xor(s, 1, 64);
    s += __shfl_xor(s, 2, 64);
    if(sub == 0) S1[g*NC_ + ch] = s;
  }
}

// ---------------- Pass 2: Newton-Schulz ----------------
__device__ __forceinline__ void mm_core(f32x4 acc[2][2],
    const unsigned short* Ah, const unsigned short* Al,
    const unsigned short* Bh, const unsigned short* Bl,
    int lane, int wrow, int wcol){
  #pragma unroll
  for(int ks = 0; ks < 2; ++ks){
    const int kbyte = ks*64 + (lane >> 4) * 16;
    s16x8 ah0 = ld_frag(Ah, wrow +      (lane & 15), kbyte);
    s16x8 ah1 = ld_frag(Ah, wrow + 16 + (lane & 15), kbyte);
    s16x8 al0 = ld_frag(Al, wrow +      (lane & 15), kbyte);
    s16x8 al1 = ld_frag(Al, wrow + 16 + (lane & 15), kbyte);
    s16x8 bh0 = ld_frag(Bh, wcol +      (lane & 15), kbyte);
    s16x8 bh1 = ld_frag(Bh, wcol + 16 + (lane & 15), kbyte);
    s16x8 bl0 = ld_frag(Bl, wcol +      (lane & 15), kbyte);
    s16x8 bl1 = ld_frag(Bl, wcol + 16 + (lane & 15), kbyte);
    MFMA_(ah0, bh0, acc[0][0]); MFMA_(ah0, bl0, acc[0][0]); MFMA_(al0, bh0, acc[0][0]);
    MFMA_(ah0, bh1, acc[0][1]); MFMA_(ah0, bl1, acc[0][1]); MFMA_(al0, bh1, acc[0][1]);
    MFMA_(ah1, bh0, acc[1][0]); MFMA_(ah1, bl0, acc[1][0]); MFMA_(al1, bh0, acc[1][0]);
    MFMA_(ah1, bh1, acc[1][1]); MFMA_(ah1, bl1, acc[1][1]); MFMA_(al1, bh1, acc[1][1]);
  }
}

__device__ __forceinline__ void mm64(unsigned short* dH, unsigned short* dL,
    const unsigned short* Ah, const unsigned short* Al,
    const unsigned short* Bh, const unsigned short* Bl,
    int lane, int wrow, int wcol){
  f32x4 acc[2][2] = {};
  mm_core(acc, Ah, Al, Bh, Bl, lane, wrow, wcol);
  #pragma unroll
  for(int i = 0; i < 2; ++i)
  #pragma unroll
  for(int j = 0; j < 2; ++j)
  #pragma unroll
  for(int r = 0; r < 4; ++r){
    const int d = wrow + 16*i + (lane >> 4)*4 + r;
    const int e = wcol + 16*j + (lane & 15);
    const float v = acc[i][j][r];
    const unsigned short h = f2bf(v);
    st_h(dH, d, e, h);
    st_h(dL, d, e, f2bf(v - bf2f(h)));
  }
}

__device__ __forceinline__ void ns_update(unsigned short* dH, unsigned short* dL,
    const unsigned short* Zh, const unsigned short* Zl,
    const unsigned short* Snh, const unsigned short* Snl,
    const unsigned short* pH, const unsigned short* pL,
    int lane, int wrow, int wcol){
  f32x4 acc[2][2] = {};
  mm_core(acc, Zh, Zl, Snh, Snl, lane, wrow, wcol);
  #pragma unroll
  for(int i = 0; i < 2; ++i)
  #pragma unroll
  for(int j = 0; j < 2; ++j)
  #pragma unroll
  for(int r = 0; r < 4; ++r){
    const int d = wrow + 16*i + (lane >> 4)*4 + r;
    const int e = wcol + 16*j + (lane & 15);
    const float pv = bf2f(ld_h(pH, d, e)) + bf2f(ld_h(pL, d, e));
    const float v = 1.5f*pv - 0.5f*acc[i][j][r];
    const unsigned short h = f2bf(v);
    st_h(dH, d, e, h);
    st_h(dL, d, e, f2bf(v - bf2f(h)));
  }
}

__global__ __launch_bounds__(256) void k_ns(const float* __restrict__ S1,
                                            const float* __restrict__ S2,
                                            const float* __restrict__ weight,
                                            const float* __restrict__ bias,
                                            float* __restrict__ wm,
                                            float* __restrict__ beta){
  __shared__ __align__(16) unsigned short smem[8*4096];   // 64 KiB exactly
  unsigned short* Snh = smem;
  unsigned short* Snl = smem + 1*4096;
  unsigned short* Xh  = smem + 2*4096;
  unsigned short* Xl  = smem + 3*4096;
  unsigned short* Yh  = smem + 4*4096;
  unsigned short* Yl  = smem + 5*4096;
  unsigned short* Zh  = smem + 6*4096;
  unsigned short* Zl  = smem + 7*4096;
  const int g = blockIdx.x, tid = threadIdx.x;
  const int lane = tid & 63, wave = tid >> 6;
  const float* S1g = S1 + g*NC_;
  const float* S2g = S2 + g*NC_*NC_;
  const float invm = 1.0f / (float)M_;

  // trace of Sigma: lane-parallel (1 diag elem / lane) + butterfly reduce
  float term;
  {
    const float mui = S1g[lane] * invm;
    term = S2g[lane*NC_ + lane]*invm - mui*mui + EPS_;
    #pragma unroll
    for(int m2 = 1; m2 < 64; m2 <<= 1) term += __shfl_xor(term, m2, 64);
  }
  const float rTr  = 1.0f / term;
  const float srtr = sqrtf(rTr);

  {
    const int d  = tid >> 2;
    const int e0 = (tid & 3) * 16;
    const float mud = S1g[d] * invm;
    for(int k = 0; k < 16; ++k){
      const int e = e0 + k;
      const float mue = S1g[e] * invm;
      const float s = (S2g[d*NC_ + e]*invm - mud*mue + ((d==e)?EPS_:0.f)) * rTr;
      const unsigned short h = f2bf(s);
      st_h(Snh, d, e, h);
      st_h(Snl, d, e, f2bf(s - bf2f(h)));
      st_h(Xh,  d, e, (d==e)?(unsigned short)0x3F80:(unsigned short)0);
      st_h(Xl,  d, e, (unsigned short)0);
    }
  }
  wg_barrier();

  unsigned short *pH = Xh, *pL = Xl, *qH = Yh, *qL = Yl;
  const int wrow = (wave >> 1)*32, wcol = (wave & 1)*32;
  for(int it = 0; it < TIT_; ++it){
    mm64(qH, qL, pH, pL, pH, pL, lane, wrow, wcol);     // T1 = P*P
    wg_barrier();
    mm64(Zh, Zl, qH, qL, pH, pL, lane, wrow, wcol);     // T2 = T1*P
    wg_barrier();
    ns_update(qH, qL, Zh, Zl, Snh, Snl, pH, pL, lane, wrow, wcol); // P' into q
    wg_barrier();
    unsigned short* t;
    t = pH; pH = qH; qH = t;
    t = pL; pL = qL; qL = t;
  }

  // wm = P*sqrt(rTr); beta = bias - weight * (wm @ mu)
  float* wmg = wm + g*NC_*NC_;
  const int d  = tid >> 2;
  const int e0 = (tid & 3) * 16;
  float rs = 0.f;
  for(int k = 0; k < 16; ++k){
    const int e = e0 + k;
    const float wv = (bf2f(ld_h(pH, d, e)) + bf2f(ld_h(pL, d, e))) * srtr;
    wmg[d*NC_ + e] = wv;
    rs += wv * (S1g[e] * invm);
  }
  rs += __shfl_xor(rs, 1, 64);
  rs += __shfl_xor(rs, 2, 64);
  if((tid & 3) == 0)
    beta[g*NC_ + d] = bias[g*NC_ + d] - weight[g*NC_ + d] * rs;
}

// ---------------- Pass 3: apply ----------------
__global__ __launch_bounds__(256) void k_apply(const float* __restrict__ x,
                                               const float* __restrict__ wm,
                                               const float* __restrict__ beta,
                                               const float* __restrict__ weight,
                                               float* __restrict__ out){
  // transposed tile: [pos][ch], rows 128B, byte ^= (pos&7)<<4
  __shared__ __align__(16) unsigned short tileT[2][64*64];
  const int tid  = threadIdx.x;
  const int lane = tid & 63, wave = tid >> 6;
  const int bx   = blockIdx.x;
  const int g = bx >> 9, sub = bx & 511, b = sub >> 3, oct = sub & 7;
  const int ck0 = (oct*49) >> 3, ck1 = ((oct+1)*49) >> 3;
  const int nck = ck1 - ck0;
  const float* xg = x   + ((size_t)b*C_ + (size_t)g*NC_) * HW_;
  float*       og = out + ((size_t)b*C_ + (size_t)g*NC_) * HW_;
  const int chb = (tid >> 4) * 4;
  const int posoff = (tid & 15) * 4;

  // wm fragments (hi/lo) in registers; wm symmetric, used as B operand.
  const float* wmg = wm + g*NC_*NC_;
  const int arow = wave*16 + (lane & 15);   // this lane's output channel
  s16x8 ah[2], al[2];
  #pragma unroll
  for(int ks = 0; ks < 2; ++ks){
    const int kc = ks*32 + (lane >> 4)*8;
    const float* p = wmg + arow*NC_ + kc;
    #pragma unroll
    for(int j = 0; j < 8; ++j){
      const float w = p[j];
      const unsigned short h = f2bf(w);
      ah[ks][j] = (short)h;
      al[ks][j] = (short)f2bf(w - bf2f(h));
    }
  }
  const int cl = wave*16 + (lane & 15);     // output channel (local)
  const float wt = weight[g*NC_ + cl];
  const float bt = beta  [g*NC_ + cl];

  float v[4][4];
  auto load_c = [&](int ck){
    #pragma unroll
    for(int q = 0; q < 4; ++q){
      const float4 t = *(const float4*)(xg + (size_t)(chb+q)*HW_ + ck*64 + posoff);
      v[q][0]=t.x; v[q][1]=t.y; v[q][2]=t.z; v[q][3]=t.w;
    }
  };
  auto write_c = [&](unsigned short* tl){
    #pragma unroll
    for(int r = 0; r < 4; ++r){
      const int p = posoff + r;
      const unsigned long long pk =
            (unsigned long long)f2bf(v[0][r])
          | ((unsigned long long)f2bf(v[1][r]) << 16)
          | ((unsigned long long)f2bf(v[2][r]) << 32)
          | ((unsigned long long)f2bf(v[3][r]) << 48);
      *(unsigned long long*)((char*)tl + p*128 + ((chb*2) ^ ((p & 7) << 4))) = pk;
    }
  };
  auto comp = [&](const unsigned short* tl, int p0){
    #pragma unroll
    for(int tn = 0; tn < 4; ++tn){
      f32x4 acc = {0.f,0.f,0.f,0.f};
      const int pos = tn*16 + (lane & 15);   // A row = position
      #pragma unroll
      for(int ks = 0; ks < 2; ++ks){
        const int cb = (ks*64 + (lane >> 4)*16) ^ ((pos & 7) << 4);
        const s16x8 afr = *(const s16x8*)((const char*)tl + pos*128 + cb);
        MFMA_(afr, ah[ks], acc);             // D[pos][ch_out]
        MFMA_(afr, al[ks], acc);
      }
      const int pr = p0 + tn*16 + ((lane >> 4) << 2);  // 4 consecutive positions
      f32x4 o;
      o[0] = acc[0]*wt + bt;
      o[1] = acc[1]*wt + bt;
      o[2] = acc[2]*wt + bt;
      o[3] = acc[3]*wt + bt;
      __builtin_nontemporal_store(o, (f32x4*)(og + (size_t)cl*HW_ + pr));
    }
  };

  // distance-2 prefetch, 2 LDS buffers; raw barrier => nt stores and the
  // prefetch loads are never force-drained at the barrier.
  load_c(ck0);
  write_c(tileT[0]);
  if(nck > 1) load_c(ck0 + 1);
  wg_barrier();
  for(int i = 0; i < nck; ++i){
    if(i + 1 < nck) write_c(tileT[(i+1)&1]);
    if(i + 2 < nck) load_c(ck0 + i + 2);
    comp(tileT[i&1], (ck0 + i)*64);
    wg_barrier();
  }
}

extern "C" void kernel_launch(void* const* d_in, const int* in_sizes, int n_in,
                              void* d_out, int out_size, void* d_ws, size_t ws_size,
                              hipStream_t stream){
  (void)in_sizes; (void)n_in; (void)out_size;
  const float* x  = (const float*)d_in[0];
  const float* w  = (const float*)d_in[1];
  const float* bs = (const float*)d_in[2];
  float* out  = (float*)d_out;
  float* S1   = (float*)d_ws;                // 256
  float* S2   = S1 + 256;                    // 4*4096
  float* beta = S2 + G_*NC_*NC_;             // 256
  float* wm   = beta + 256;                  // 4*4096
  float* p2   = wm + G_*NC_*NC_;             // NGB_*4096
  float* p1   = p2 + (size_t)NGB_*4096;      // NGB_*64
  const size_t need = ((size_t)(256 + G_*4096 + 256 + G_*4096)
                       + (size_t)NGB_*4096 + (size_t)NGB_*64) * sizeof(float);
  if(ws_size >= need){
    k_gram<false><<<NGB_, 256, 0, stream>>>(x, S1, S2, p2, p1);
    k_reduce<<<260, 256, 0, stream>>>(p2, p1, S1, S2);
  }else{
    hipError_t _e = hipMemsetAsync(d_ws, 0, (256 + G_*NC_*NC_)*sizeof(float), stream);
    (void)_e;
    k_gram<true><<<NGB_, 256, 0, stream>>>(x, S1, S2, p2, p1);
  }
  k_ns   <<<G_,   256, 0, stream>>>(S1, S2, w, bs, wm, beta);
  k_apply<<<2048, 256, 0, stream>>>(x, wm, beta, w, out);
}

// Round 9
// 140.557 us; speedup vs baseline: 1.1154x; 1.0701x over previous
//
#include <hip/hip_runtime.h>
#include <hip/hip_bf16.h>

// IterNorm: x(64,256,56,56) fp32 -> whiten per 64-ch group (4 groups) via
// Newton-Schulz (T=5), then *weight + bias.
//
// Pass 1:  k_gram   -- per-group gram + channel sums; partials coalesced in
//                      MFMA-native layout (no atomics). 512 blocks (2/CU),
//                      distance-2 prefetch, double-buffered LDS, raw barrier.
// Pass 1b: k_reduce -- sums 128 partials/element -> S1, S2 (deterministic).
// Pass 2:  k_ns     -- Sigma -> Sn -> 5 NS iters -> wm' = wm*srtr*w,
//                      beta = b - wm'@mu (split hi/lo bf16 MFMA).
// Pass 3:  k_apply  -- out = (wm' @ x) + beta; operand-swapped MFMA, 1024
//                      blocks, distance-2 prefetch, 2-buffer LDS, nt stores.

#define B_    64
#define C_    256
#define HW_   3136
#define G_    4
#define NC_   64
#define M_    (B_*HW_)          // 200704
#define EPS_  1e-5f
#define TIT_  5

#define NGB_  512               // gram blocks: (g, b, half)
#define PBLK_ 128               // gram blocks per group

typedef __attribute__((ext_vector_type(8))) short  s16x8;
typedef __attribute__((ext_vector_type(4))) float  f32x4;

#define MFMA_(A,Bv,Cc) Cc = __builtin_amdgcn_mfma_f32_16x16x32_bf16(A, Bv, Cc, 0, 0, 0)

// Workgroup barrier WITHOUT vmcnt(0) drain: LDS writes made visible, global
// loads/stores stay in flight (compiler inserts precise vmcnt at use sites).
__device__ __forceinline__ void wg_barrier(){
  asm volatile("s_waitcnt lgkmcnt(0)" ::: "memory");
  __builtin_amdgcn_s_barrier();
}

__device__ __forceinline__ unsigned short f2bf(float f){
  union{ float f; unsigned int u; } c; c.f = f;
  unsigned int u = c.u;
  u = u + 0x7FFFu + ((u >> 16) & 1u);
  return (unsigned short)(u >> 16);
}
__device__ __forceinline__ float bf2f(unsigned short h){
  union{ unsigned int u; float f; } c; c.u = ((unsigned int)h) << 16;
  return c.f;
}
// XOR swizzle for [row][64] bf16 tiles read column-wise (gram / NS).
__device__ __forceinline__ int swz(int off, int row){
  return off ^ ((row & 7) << 4) ^ (((row >> 3) & 3) << 5);
}
__device__ __forceinline__ s16x8 ld_frag(const unsigned short* base, int row, int kbyte){
  return *(const s16x8*)((const char*)base + swz(row*128 + kbyte, row));
}
__device__ __forceinline__ void st_h(unsigned short* base, int row, int col, unsigned short v){
  *(unsigned short*)((char*)base + swz(row*128 + col*2, row)) = v;
}
__device__ __forceinline__ unsigned short ld_h(const unsigned short* base, int row, int col){
  return *(const unsigned short*)((const char*)base + swz(row*128 + col*2, row));
}

// ---------------- Pass 1: gram + sums ----------------
template<bool ATOMIC>
__global__ __launch_bounds__(256) void k_gram(const float* __restrict__ x,
                                              float* __restrict__ S1,
                                              float* __restrict__ S2,
                                              float* __restrict__ partS2,
                                              float* __restrict__ partS1){
  __shared__ __align__(16) unsigned short tile[2][64*64];
  const int tid  = threadIdx.x;
  const int lane = tid & 63, wave = tid >> 6;
  const int bx   = blockIdx.x;
  const int g = bx >> 7, sub = bx & 127, b = sub >> 1, half = sub & 1;
  const int ck0 = half ? 24 : 0, ck1 = half ? 49 : 24;
  const int nck = ck1 - ck0;
  const float* xg = x + ((size_t)b*C_ + (size_t)g*NC_) * HW_;
  const int chb = (tid >> 4) * 4;       // this thread's 4 channels: chb+q
  const int posoff = (tid & 15) * 4;
  const int wrow = (wave >> 1) * 32, wcol = (wave & 1) * 32;
  float s1a[4] = {0.f,0.f,0.f,0.f};
  f32x4 acc[2][2] = {};
  float v[4][4];

  auto load_c = [&](int ck){
    #pragma unroll
    for(int q = 0; q < 4; ++q){
      const float4 t = *(const float4*)(xg + (size_t)(chb+q)*HW_ + ck*64 + posoff);
      v[q][0]=t.x; v[q][1]=t.y; v[q][2]=t.z; v[q][3]=t.w;
    }
  };
  auto write_c = [&](unsigned short* tl){
    #pragma unroll
    for(int q = 0; q < 4; ++q){
      s1a[q] += v[q][0]+v[q][1]+v[q][2]+v[q][3];
      const int ch = chb + q;
      const unsigned long long pk =
            (unsigned long long)f2bf(v[q][0])
          | ((unsigned long long)f2bf(v[q][1]) << 16)
          | ((unsigned long long)f2bf(v[q][2]) << 32)
          | ((unsigned long long)f2bf(v[q][3]) << 48);
      *(unsigned long long*)((char*)tl + swz(ch*128 + posoff*2, ch)) = pk;
    }
  };
  auto comp = [&](const unsigned short* tl){
    #pragma unroll
    for(int ks = 0; ks < 2; ++ks){
      const int kbyte = ks*64 + (lane >> 4) * 16;
      s16x8 a0 = ld_frag(tl, wrow +      (lane & 15), kbyte);
      s16x8 a1 = ld_frag(tl, wrow + 16 + (lane & 15), kbyte);
      s16x8 b0 = ld_frag(tl, wcol +      (lane & 15), kbyte);
      s16x8 b1 = ld_frag(tl, wcol + 16 + (lane & 15), kbyte);
      MFMA_(a0, b0, acc[0][0]);
      MFMA_(a0, b1, acc[0][1]);
      MFMA_(a1, b0, acc[1][0]);
      MFMA_(a1, b1, acc[1][1]);
    }
  };

  // distance-2 prefetch, 2 LDS buffers: at iter i publish chunk i+1
  // (that buffer was last *read* at iter i-1, behind the barrier),
  // issue loads for i+2, compute chunk i.
  load_c(ck0);
  write_c(tile[0]);
  if(nck > 1) load_c(ck0 + 1);
  wg_barrier();
  for(int i = 0; i < nck; ++i){
    if(i + 1 < nck) write_c(tile[(i+1)&1]);
    if(i + 2 < nck) load_c(ck0 + i + 2);
    comp(tile[i&1]);
    wg_barrier();
  }

  if(ATOMIC){
    float* S2g = S2 + g * (NC_*NC_);
    #pragma unroll
    for(int i = 0; i < 2; ++i)
    #pragma unroll
    for(int j = 0; j < 2; ++j)
    #pragma unroll
    for(int r = 0; r < 4; ++r){
      const int d = wrow + 16*i + (lane >> 4)*4 + r;
      const int e = wcol + 16*j + (lane & 15);
      atomicAdd(&S2g[d*NC_ + e], acc[i][j][r]);
    }
  }else{
    // MFMA-native layout: fully coalesced float4 stream, no remap here.
    float* p2 = partS2 + (size_t)bx*4096 + tid*16;
    #pragma unroll
    for(int i = 0; i < 2; ++i)
    #pragma unroll
    for(int j = 0; j < 2; ++j)
      *(f32x4*)(p2 + (i*2+j)*4) = acc[i][j];
  }
  #pragma unroll
  for(int q = 0; q < 4; ++q){
    float s = s1a[q];
    #pragma unroll
    for(int m2 = 1; m2 < 16; m2 <<= 1) s += __shfl_xor(s, m2, 64);
    if((lane & 15) == 0){
      if(ATOMIC) atomicAdd(&S1[g*NC_ + chb + q], s);
      else       partS1[(size_t)bx*64 + chb + q] = s;
    }
  }
}

// ---------------- Pass 1b: reduce partials ----------------
// 260 blocks: 0..255 handle S2 (4 threads/element x 32 partials each),
// 256..259 handle S1 (one group per block). Deterministic order.
__global__ __launch_bounds__(256) void k_reduce(const float* __restrict__ partS2,
                                                const float* __restrict__ partS1,
                                                float* __restrict__ S1,
                                                float* __restrict__ S2){
  const int bid = blockIdx.x, tid = threadIdx.x;
  const int sub = tid & 3;
  if(bid < 256){
    const int flat = (bid*256 + tid) >> 2;   // element 0..16383
    const int g = flat >> 12, t = flat & 4095;
    const float* p = partS2 + ((size_t)(g*PBLK_ + sub*(PBLK_/4)))*4096 + t;
    float s = 0.f;
    for(int jb = 0; jb < PBLK_/4; ++jb) s += p[(size_t)jb*4096];
    s += __shfl_xor(s, 1, 64);
    s += __shfl_xor(s, 2, 64);
    if(sub == 0){
      // invert MFMA-native layout -> (d,e)
      const int tt = t >> 4, q = (t >> 2) & 3, r = t & 3;
      const int wave = tt >> 6, lane = tt & 63;
      const int d = (wave >> 1)*32 + ((q >> 1) << 4) + ((lane >> 4) << 2) + r;
      const int e = (wave &  1)*32 + ((q &  1) << 4) + (lane & 15);
      S2[g*4096 + d*64 + e] = s;
    }
  }else{
    const int g = bid - 256, ch = tid >> 2;
    const float* p = partS1 + ((size_t)(g*PBLK_ + sub*(PBLK_/4)))*64 + ch;
    float s = 0.f;
    for(int jb = 0; jb < PBLK_/4; ++jb) s += p[(size_t)jb*64];
    s += __shfl_xor(s, 1, 64);
    s += __shfl_xor(s, 2, 64);
    if(sub == 0) S1[g*NC_ + ch] = s;
  }
}

// ---------------- Pass 2: Newton-Schulz ----------------
__device__ __forceinline__ void mm_core(f32x4 acc[2][2],
    const unsigned short* Ah, const unsigned short* Al,
    const unsigned short* Bh, const unsigned short* Bl,
    int lane, int wrow, int wcol){
  #pragma unroll
  for(int ks = 0; ks < 2; ++ks){
    const int kbyte = ks*64 + (lane >> 4) * 16;
    s16x8 ah0 = ld_frag(Ah, wrow +      (lane & 15), kbyte);
    s16x8 ah1 = ld_frag(Ah, wrow + 16 + (lane & 15), kbyte);
    s16x8 al0 = ld_frag(Al, wrow +      (lane & 15), kbyte);
    s16x8 al1 = ld_frag(Al, wrow + 16 + (lane & 15), kbyte);
    s16x8 bh0 = ld_frag(Bh, wcol +      (lane & 15), kbyte);
    s16x8 bh1 = ld_frag(Bh, wcol + 16 + (lane & 15), kbyte);
    s16x8 bl0 = ld_frag(Bl, wcol +      (lane & 15), kbyte);
    s16x8 bl1 = ld_frag(Bl, wcol + 16 + (lane & 15), kbyte);
    MFMA_(ah0, bh0, acc[0][0]); MFMA_(ah0, bl0, acc[0][0]); MFMA_(al0, bh0, acc[0][0]);
    MFMA_(ah0, bh1, acc[0][1]); MFMA_(ah0, bl1, acc[0][1]); MFMA_(al0, bh1, acc[0][1]);
    MFMA_(ah1, bh0, acc[1][0]); MFMA_(ah1, bl0, acc[1][0]); MFMA_(al1, bh0, acc[1][0]);
    MFMA_(ah1, bh1, acc[1][1]); MFMA_(ah1, bl1, acc[1][1]); MFMA_(al1, bh1, acc[1][1]);
  }
}

__device__ __forceinline__ void mm64(unsigned short* dH, unsigned short* dL,
    const unsigned short* Ah, const unsigned short* Al,
    const unsigned short* Bh, const unsigned short* Bl,
    int lane, int wrow, int wcol){
  f32x4 acc[2][2] = {};
  mm_core(acc, Ah, Al, Bh, Bl, lane, wrow, wcol);
  #pragma unroll
  for(int i = 0; i < 2; ++i)
  #pragma unroll
  for(int j = 0; j < 2; ++j)
  #pragma unroll
  for(int r = 0; r < 4; ++r){
    const int d = wrow + 16*i + (lane >> 4)*4 + r;
    const int e = wcol + 16*j + (lane & 15);
    const float v = acc[i][j][r];
    const unsigned short h = f2bf(v);
    st_h(dH, d, e, h);
    st_h(dL, d, e, f2bf(v - bf2f(h)));
  }
}

__device__ __forceinline__ void ns_update(unsigned short* dH, unsigned short* dL,
    const unsigned short* Zh, const unsigned short* Zl,
    const unsigned short* Snh, const unsigned short* Snl,
    const unsigned short* pH, const unsigned short* pL,
    int lane, int wrow, int wcol){
  f32x4 acc[2][2] = {};
  mm_core(acc, Zh, Zl, Snh, Snl, lane, wrow, wcol);
  #pragma unroll
  for(int i = 0; i < 2; ++i)
  #pragma unroll
  for(int j = 0; j < 2; ++j)
  #pragma unroll
  for(int r = 0; r < 4; ++r){
    const int d = wrow + 16*i + (lane >> 4)*4 + r;
    const int e = wcol + 16*j + (lane & 15);
    const float pv = bf2f(ld_h(pH, d, e)) + bf2f(ld_h(pL, d, e));
    const float v = 1.5f*pv - 0.5f*acc[i][j][r];
    const unsigned short h = f2bf(v);
    st_h(dH, d, e, h);
    st_h(dL, d, e, f2bf(v - bf2f(h)));
  }
}

__global__ __launch_bounds__(256) void k_ns(const float* __restrict__ S1,
                                            const float* __restrict__ S2,
                                            const float* __restrict__ weight,
                                            const float* __restrict__ bias,
                                            float* __restrict__ wm,
                                            float* __restrict__ beta){
  __shared__ __align__(16) unsigned short smem[8*4096];   // 64 KiB exactly
  unsigned short* Snh = smem;
  unsigned short* Snl = smem + 1*4096;
  unsigned short* Xh  = smem + 2*4096;
  unsigned short* Xl  = smem + 3*4096;
  unsigned short* Yh  = smem + 4*4096;
  unsigned short* Yl  = smem + 5*4096;
  unsigned short* Zh  = smem + 6*4096;
  unsigned short* Zl  = smem + 7*4096;
  const int g = blockIdx.x, tid = threadIdx.x;
  const int lane = tid & 63, wave = tid >> 6;
  const float* S1g = S1 + g*NC_;
  const float* S2g = S2 + g*NC_*NC_;
  const float invm = 1.0f / (float)M_;

  // trace of Sigma: lane-parallel (1 diag elem / lane) + butterfly reduce
  float term;
  {
    const float mui = S1g[lane] * invm;
    term = S2g[lane*NC_ + lane]*invm - mui*mui + EPS_;
    #pragma unroll
    for(int m2 = 1; m2 < 64; m2 <<= 1) term += __shfl_xor(term, m2, 64);
  }
  const float rTr  = 1.0f / term;
  const float srtr = sqrtf(rTr);

  {
    const int d  = tid >> 2;
    const int e0 = (tid & 3) * 16;
    const float mud = S1g[d] * invm;
    for(int k = 0; k < 16; ++k){
      const int e = e0 + k;
      const float mue = S1g[e] * invm;
      const float s = (S2g[d*NC_ + e]*invm - mud*mue + ((d==e)?EPS_:0.f)) * rTr;
      const unsigned short h = f2bf(s);
      st_h(Snh, d, e, h);
      st_h(Snl, d, e, f2bf(s - bf2f(h)));
      st_h(Xh,  d, e, (d==e)?(unsigned short)0x3F80:(unsigned short)0);
      st_h(Xl,  d, e, (unsigned short)0);
    }
  }
  wg_barrier();

  unsigned short *pH = Xh, *pL = Xl, *qH = Yh, *qL = Yl;
  const int wrow = (wave >> 1)*32, wcol = (wave & 1)*32;
  for(int it = 0; it < TIT_; ++it){
    mm64(qH, qL, pH, pL, pH, pL, lane, wrow, wcol);     // T1 = P*P
    wg_barrier();
    mm64(Zh, Zl, qH, qL, pH, pL, lane, wrow, wcol);     // T2 = T1*P
    wg_barrier();
    ns_update(qH, qL, Zh, Zl, Snh, Snl, pH, pL, lane, wrow, wcol); // P' into q
    wg_barrier();
    unsigned short* t;
    t = pH; pH = qH; qH = t;
    t = pL; pL = qL; qL = t;
  }

  // wm' = P*sqrt(rTr)*w[d]; beta = bias - wm'@mu  (weight folded into wm)
  float* wmg = wm + g*NC_*NC_;
  const int d  = tid >> 2;
  const int e0 = (tid & 3) * 16;
  const float wd = weight[g*NC_ + d] * srtr;
  float rs = 0.f;
  for(int k = 0; k < 16; ++k){
    const int e = e0 + k;
    const float wv = (bf2f(ld_h(pH, d, e)) + bf2f(ld_h(pL, d, e))) * wd;
    wmg[d*NC_ + e] = wv;
    rs += wv * (S1g[e] * invm);
  }
  rs += __shfl_xor(rs, 1, 64);
  rs += __shfl_xor(rs, 2, 64);
  if((tid & 3) == 0)
    beta[g*NC_ + d] = bias[g*NC_ + d] - rs;
}

// ---------------- Pass 3: apply ----------------
__global__ __launch_bounds__(256) void k_apply(const float* __restrict__ x,
                                               const float* __restrict__ wm,
                                               const float* __restrict__ beta,
                                               float* __restrict__ out){
  // transposed tile: [pos][ch], rows 128B, byte ^= (pos&7)<<4
  __shared__ __align__(16) unsigned short tileT[2][64*64];
  const int tid  = threadIdx.x;
  const int lane = tid & 63, wave = tid >> 6;
  const int bx   = blockIdx.x;
  const int g = bx >> 8, sub = bx & 255, b = sub >> 2, quad = sub & 3;
  const int ck0 = (quad*49) >> 2, ck1 = ((quad+1)*49) >> 2;
  const int nck = ck1 - ck0;
  const float* xg = x   + ((size_t)b*C_ + (size_t)g*NC_) * HW_;
  float*       og = out + ((size_t)b*C_ + (size_t)g*NC_) * HW_;
  const int chb = (tid >> 4) * 4;
  const int posoff = (tid & 15) * 4;

  // wm' fragments (hi/lo) in registers; wm' symmetric-scaled, B operand.
  const float* wmg = wm + g*NC_*NC_;
  const int arow = wave*16 + (lane & 15);   // this lane's output channel
  s16x8 ah[2], al[2];
  #pragma unroll
  for(int ks = 0; ks < 2; ++ks){
    const int kc = ks*32 + (lane >> 4)*8;
    const float* p = wmg + arow*NC_ + kc;
    #pragma unroll
    for(int j = 0; j < 8; ++j){
      const float w = p[j];
      const unsigned short h = f2bf(w);
      ah[ks][j] = (short)h;
      al[ks][j] = (short)f2bf(w - bf2f(h));
    }
  }
  const int cl = wave*16 + (lane & 15);     // output channel (local)
  const float bt = beta[g*NC_ + cl];

  float v[4][4];
  auto load_c = [&](int ck){
    #pragma unroll
    for(int q = 0; q < 4; ++q){
      const float4 t = *(const float4*)(xg + (size_t)(chb+q)*HW_ + ck*64 + posoff);
      v[q][0]=t.x; v[q][1]=t.y; v[q][2]=t.z; v[q][3]=t.w;
    }
  };
  auto write_c = [&](unsigned short* tl){
    #pragma unroll
    for(int r = 0; r < 4; ++r){
      const int p = posoff + r;
      const unsigned long long pk =
            (unsigned long long)f2bf(v[0][r])
          | ((unsigned long long)f2bf(v[1][r]) << 16)
          | ((unsigned long long)f2bf(v[2][r]) << 32)
          | ((unsigned long long)f2bf(v[3][r]) << 48);
      *(unsigned long long*)((char*)tl + p*128 + ((chb*2) ^ ((p & 7) << 4))) = pk;
    }
  };
  auto comp = [&](const unsigned short* tl, int p0){
    #pragma unroll
    for(int tn = 0; tn < 4; ++tn){
      f32x4 acc = {0.f,0.f,0.f,0.f};
      const int pos = tn*16 + (lane & 15);   // A row = position
      #pragma unroll
      for(int ks = 0; ks < 2; ++ks){
        const int cb = (ks*64 + (lane >> 4)*16) ^ ((pos & 7) << 4);
        const s16x8 afr = *(const s16x8*)((const char*)tl + pos*128 + cb);
        MFMA_(afr, ah[ks], acc);             // D[pos][ch_out]
        MFMA_(afr, al[ks], acc);
      }
      const int pr = p0 + tn*16 + ((lane >> 4) << 2);  // 4 consecutive positions
      f32x4 o;
      o[0] = acc[0] + bt;
      o[1] = acc[1] + bt;
      o[2] = acc[2] + bt;
      o[3] = acc[3] + bt;
      __builtin_nontemporal_store(o, (f32x4*)(og + (size_t)cl*HW_ + pr));
    }
  };

  // distance-2 prefetch, 2 LDS buffers; raw barrier keeps loads/stores in flight
  load_c(ck0);
  write_c(tileT[0]);
  if(nck > 1) load_c(ck0 + 1);
  wg_barrier();
  for(int i = 0; i < nck; ++i){
    if(i + 1 < nck) write_c(tileT[(i+1)&1]);
    if(i + 2 < nck) load_c(ck0 + i + 2);
    comp(tileT[i&1], (ck0 + i)*64);
    wg_barrier();
  }
}

extern "C" void kernel_launch(void* const* d_in, const int* in_sizes, int n_in,
                              void* d_out, int out_size, void* d_ws, size_t ws_size,
                              hipStream_t stream){
  (void)in_sizes; (void)n_in; (void)out_size;
  const float* x  = (const float*)d_in[0];
  const float* w  = (const float*)d_in[1];
  const float* bs = (const float*)d_in[2];
  float* out  = (float*)d_out;
  float* S1   = (float*)d_ws;                // 256
  float* S2   = S1 + 256;                    // 4*4096
  float* beta = S2 + G_*NC_*NC_;             // 256
  float* wm   = beta + 256;                  // 4*4096
  float* p2   = wm + G_*NC_*NC_;             // NGB_*4096
  float* p1   = p2 + (size_t)NGB_*4096;      // NGB_*64
  const size_t need = ((size_t)(256 + G_*4096 + 256 + G_*4096)
                       + (size_t)NGB_*4096 + (size_t)NGB_*64) * sizeof(float);
  if(ws_size >= need){
    k_gram<false><<<NGB_, 256, 0, stream>>>(x, S1, S2, p2, p1);
    k_reduce<<<260, 256, 0, stream>>>(p2, p1, S1, S2);
  }else{
    hipError_t _e = hipMemsetAsync(d_ws, 0, (256 + G_*NC_*NC_)*sizeof(float), stream);
    (void)_e;
    k_gram<true><<<NGB_, 256, 0, stream>>>(x, S1, S2, p2, p1);
  }
  k_ns   <<<G_,   256, 0, stream>>>(S1, S2, w, bs, wm, beta);
  k_apply<<<1024, 256, 0, stream>>>(x, wm, beta, out);
}

// Round 11
// 136.994 us; speedup vs baseline: 1.1444x; 1.0260x over previous
//
#include <hip/hip_runtime.h>
#include <hip/hip_bf16.h>

// IterNorm: x(64,256,56,56) fp32 -> whiten per 64-ch group (4 groups) via
// Newton-Schulz (T=5), then *weight + bias.
//
// Pass 1:  k_gram   -- per-group gram + channel sums; partials coalesced in
//                      MFMA-native layout (no atomics). 512 blocks (2/CU),
//                      distance-2 prefetch, double-buffered LDS, raw barrier.
// Pass 1b: k_reduce -- sums 128 partials/element -> S1, S2 (deterministic).
// Pass 2:  k_ns     -- Sigma -> Sn -> 5 NS iters -> wm' = wm*srtr*w,
//                      beta = b - wm'@mu (split hi/lo bf16 MFMA).
// Pass 3:  k_apply  -- out = (wm' @ x) + beta; operand-swapped MFMA, 512
//                      blocks (2/CU, 24-25 chunks), distance-2 prefetch,
//                      2-buffer LDS, nt stores.

#define B_    64
#define C_    256
#define HW_   3136
#define G_    4
#define NC_   64
#define M_    (B_*HW_)          // 200704
#define EPS_  1e-5f
#define TIT_  5

#define NGB_  512               // gram blocks: (g, b, half)
#define PBLK_ 128               // gram blocks per group

typedef __attribute__((ext_vector_type(8))) short  s16x8;
typedef __attribute__((ext_vector_type(4))) float  f32x4;

#define MFMA_(A,Bv,Cc) Cc = __builtin_amdgcn_mfma_f32_16x16x32_bf16(A, Bv, Cc, 0, 0, 0)

// Workgroup barrier WITHOUT vmcnt(0) drain: LDS writes made visible, global
// loads/stores stay in flight (compiler inserts precise vmcnt at use sites).
__device__ __forceinline__ void wg_barrier(){
  asm volatile("s_waitcnt lgkmcnt(0)" ::: "memory");
  __builtin_amdgcn_s_barrier();
}

__device__ __forceinline__ unsigned short f2bf(float f){
  union{ float f; unsigned int u; } c; c.f = f;
  unsigned int u = c.u;
  u = u + 0x7FFFu + ((u >> 16) & 1u);
  return (unsigned short)(u >> 16);
}
__device__ __forceinline__ float bf2f(unsigned short h){
  union{ unsigned int u; float f; } c; c.u = ((unsigned int)h) << 16;
  return c.f;
}
// XOR swizzle for [row][64] bf16 tiles read column-wise (gram / NS).
__device__ __forceinline__ int swz(int off, int row){
  return off ^ ((row & 7) << 4) ^ (((row >> 3) & 3) << 5);
}
__device__ __forceinline__ s16x8 ld_frag(const unsigned short* base, int row, int kbyte){
  return *(const s16x8*)((const char*)base + swz(row*128 + kbyte, row));
}
__device__ __forceinline__ void st_h(unsigned short* base, int row, int col, unsigned short v){
  *(unsigned short*)((char*)base + swz(row*128 + col*2, row)) = v;
}
__device__ __forceinline__ unsigned short ld_h(const unsigned short* base, int row, int col){
  return *(const unsigned short*)((const char*)base + swz(row*128 + col*2, row));
}

// ---------------- Pass 1: gram + sums ----------------
template<bool ATOMIC>
__global__ __launch_bounds__(256) void k_gram(const float* __restrict__ x,
                                              float* __restrict__ S1,
                                              float* __restrict__ S2,
                                              float* __restrict__ partS2,
                                              float* __restrict__ partS1){
  __shared__ __align__(16) unsigned short tile[2][64*64];
  const int tid  = threadIdx.x;
  const int lane = tid & 63, wave = tid >> 6;
  const int bx   = blockIdx.x;
  const int g = bx >> 7, sub = bx & 127, b = sub >> 1, half = sub & 1;
  const int ck0 = half ? 24 : 0, ck1 = half ? 49 : 24;
  const int nck = ck1 - ck0;
  const float* xg = x + ((size_t)b*C_ + (size_t)g*NC_) * HW_;
  const int chb = (tid >> 4) * 4;       // this thread's 4 channels: chb+q
  const int posoff = (tid & 15) * 4;
  const int wrow = (wave >> 1) * 32, wcol = (wave & 1) * 32;
  float s1a[4] = {0.f,0.f,0.f,0.f};
  f32x4 acc[2][2] = {};
  float v[4][4];

  auto load_c = [&](int ck){
    #pragma unroll
    for(int q = 0; q < 4; ++q){
      const float4 t = *(const float4*)(xg + (size_t)(chb+q)*HW_ + ck*64 + posoff);
      v[q][0]=t.x; v[q][1]=t.y; v[q][2]=t.z; v[q][3]=t.w;
    }
  };
  auto write_c = [&](unsigned short* tl){
    #pragma unroll
    for(int q = 0; q < 4; ++q){
      s1a[q] += v[q][0]+v[q][1]+v[q][2]+v[q][3];
      const int ch = chb + q;
      const unsigned long long pk =
            (unsigned long long)f2bf(v[q][0])
          | ((unsigned long long)f2bf(v[q][1]) << 16)
          | ((unsigned long long)f2bf(v[q][2]) << 32)
          | ((unsigned long long)f2bf(v[q][3]) << 48);
      *(unsigned long long*)((char*)tl + swz(ch*128 + posoff*2, ch)) = pk;
    }
  };
  auto comp = [&](const unsigned short* tl){
    #pragma unroll
    for(int ks = 0; ks < 2; ++ks){
      const int kbyte = ks*64 + (lane >> 4) * 16;
      s16x8 a0 = ld_frag(tl, wrow +      (lane & 15), kbyte);
      s16x8 a1 = ld_frag(tl, wrow + 16 + (lane & 15), kbyte);
      s16x8 b0 = ld_frag(tl, wcol +      (lane & 15), kbyte);
      s16x8 b1 = ld_frag(tl, wcol + 16 + (lane & 15), kbyte);
      MFMA_(a0, b0, acc[0][0]);
      MFMA_(a0, b1, acc[0][1]);
      MFMA_(a1, b0, acc[1][0]);
      MFMA_(a1, b1, acc[1][1]);
    }
  };

  // distance-2 prefetch, 2 LDS buffers: at iter i publish chunk i+1
  // (that buffer was last *read* at iter i-1, behind the barrier),
  // issue loads for i+2, compute chunk i.
  load_c(ck0);
  write_c(tile[0]);
  if(nck > 1) load_c(ck0 + 1);
  wg_barrier();
  for(int i = 0; i < nck; ++i){
    if(i + 1 < nck) write_c(tile[(i+1)&1]);
    if(i + 2 < nck) load_c(ck0 + i + 2);
    comp(tile[i&1]);
    wg_barrier();
  }

  if(ATOMIC){
    float* S2g = S2 + g * (NC_*NC_);
    #pragma unroll
    for(int i = 0; i < 2; ++i)
    #pragma unroll
    for(int j = 0; j < 2; ++j)
    #pragma unroll
    for(int r = 0; r < 4; ++r){
      const int d = wrow + 16*i + (lane >> 4)*4 + r;
      const int e = wcol + 16*j + (lane & 15);
      atomicAdd(&S2g[d*NC_ + e], acc[i][j][r]);
    }
  }else{
    // MFMA-native layout: fully coalesced float4 stream, no remap here.
    float* p2 = partS2 + (size_t)bx*4096 + tid*16;
    #pragma unroll
    for(int i = 0; i < 2; ++i)
    #pragma unroll
    for(int j = 0; j < 2; ++j)
      *(f32x4*)(p2 + (i*2+j)*4) = acc[i][j];
  }
  #pragma unroll
  for(int q = 0; q < 4; ++q){
    float s = s1a[q];
    #pragma unroll
    for(int m2 = 1; m2 < 16; m2 <<= 1) s += __shfl_xor(s, m2, 64);
    if((lane & 15) == 0){
      if(ATOMIC) atomicAdd(&S1[g*NC_ + chb + q], s);
      else       partS1[(size_t)bx*64 + chb + q] = s;
    }
  }
}

// ---------------- Pass 1b: reduce partials ----------------
// 260 blocks: 0..255 handle S2 (4 threads/element x 32 partials each),
// 256..259 handle S1 (one group per block). Deterministic order.
__global__ __launch_bounds__(256) void k_reduce(const float* __restrict__ partS2,
                                                const float* __restrict__ partS1,
                                                float* __restrict__ S1,
                                                float* __restrict__ S2){
  const int bid = blockIdx.x, tid = threadIdx.x;
  const int sub = tid & 3;
  if(bid < 256){
    const int flat = (bid*256 + tid) >> 2;   // element 0..16383
    const int g = flat >> 12, t = flat & 4095;
    const float* p = partS2 + ((size_t)(g*PBLK_ + sub*(PBLK_/4)))*4096 + t;
    float s = 0.f;
    for(int jb = 0; jb < PBLK_/4; ++jb) s += p[(size_t)jb*4096];
    s += __shfl_xor(s, 1, 64);
    s += __shfl_xor(s, 2, 64);
    if(sub == 0){
      // invert MFMA-native layout -> (d,e)
      const int tt = t >> 4, q = (t >> 2) & 3, r = t & 3;
      const int wave = tt >> 6, lane = tt & 63;
      const int d = (wave >> 1)*32 + ((q >> 1) << 4) + ((lane >> 4) << 2) + r;
      const int e = (wave &  1)*32 + ((q &  1) << 4) + (lane & 15);
      S2[g*4096 + d*64 + e] = s;
    }
  }else{
    const int g = bid - 256, ch = tid >> 2;
    const float* p = partS1 + ((size_t)(g*PBLK_ + sub*(PBLK_/4)))*64 + ch;
    float s = 0.f;
    for(int jb = 0; jb < PBLK_/4; ++jb) s += p[(size_t)jb*64];
    s += __shfl_xor(s, 1, 64);
    s += __shfl_xor(s, 2, 64);
    if(sub == 0) S1[g*NC_ + ch] = s;
  }
}

// ---------------- Pass 2: Newton-Schulz ----------------
__device__ __forceinline__ void mm_core(f32x4 acc[2][2],
    const unsigned short* Ah, const unsigned short* Al,
    const unsigned short* Bh, const unsigned short* Bl,
    int lane, int wrow, int wcol){
  #pragma unroll
  for(int ks = 0; ks < 2; ++ks){
    const int kbyte = ks*64 + (lane >> 4) * 16;
    s16x8 ah0 = ld_frag(Ah, wrow +      (lane & 15), kbyte);
    s16x8 ah1 = ld_frag(Ah, wrow + 16 + (lane & 15), kbyte);
    s16x8 al0 = ld_frag(Al, wrow +      (lane & 15), kbyte);
    s16x8 al1 = ld_frag(Al, wrow + 16 + (lane & 15), kbyte);
    s16x8 bh0 = ld_frag(Bh, wcol +      (lane & 15), kbyte);
    s16x8 bh1 = ld_frag(Bh, wcol + 16 + (lane & 15), kbyte);
    s16x8 bl0 = ld_frag(Bl, wcol +      (lane & 15), kbyte);
    s16x8 bl1 = ld_frag(Bl, wcol + 16 + (lane & 15), kbyte);
    MFMA_(ah0, bh0, acc[0][0]); MFMA_(ah0, bl0, acc[0][0]); MFMA_(al0, bh0, acc[0][0]);
    MFMA_(ah0, bh1, acc[0][1]); MFMA_(ah0, bl1, acc[0][1]); MFMA_(al0, bh1, acc[0][1]);
    MFMA_(ah1, bh0, acc[1][0]); MFMA_(ah1, bl0, acc[1][0]); MFMA_(al1, bh0, acc[1][0]);
    MFMA_(ah1, bh1, acc[1][1]); MFMA_(ah1, bl1, acc[1][1]); MFMA_(al1, bh1, acc[1][1]);
  }
}

__device__ __forceinline__ void mm64(unsigned short* dH, unsigned short* dL,
    const unsigned short* Ah, const unsigned short* Al,
    const unsigned short* Bh, const unsigned short* Bl,
    int lane, int wrow, int wcol){
  f32x4 acc[2][2] = {};
  mm_core(acc, Ah, Al, Bh, Bl, lane, wrow, wcol);
  #pragma unroll
  for(int i = 0; i < 2; ++i)
  #pragma unroll
  for(int j = 0; j < 2; ++j)
  #pragma unroll
  for(int r = 0; r < 4; ++r){
    const int d = wrow + 16*i + (lane >> 4)*4 + r;
    const int e = wcol + 16*j + (lane & 15);
    const float v = acc[i][j][r];
    const unsigned short h = f2bf(v);
    st_h(dH, d, e, h);
    st_h(dL, d, e, f2bf(v - bf2f(h)));
  }
}

__device__ __forceinline__ void ns_update(unsigned short* dH, unsigned short* dL,
    const unsigned short* Zh, const unsigned short* Zl,
    const unsigned short* Snh, const unsigned short* Snl,
    const unsigned short* pH, const unsigned short* pL,
    int lane, int wrow, int wcol){
  f32x4 acc[2][2] = {};
  mm_core(acc, Zh, Zl, Snh, Snl, lane, wrow, wcol);
  #pragma unroll
  for(int i = 0; i < 2; ++i)
  #pragma unroll
  for(int j = 0; j < 2; ++j)
  #pragma unroll
  for(int r = 0; r < 4; ++r){
    const int d = wrow + 16*i + (lane >> 4)*4 + r;
    const int e = wcol + 16*j + (lane & 15);
    const float pv = bf2f(ld_h(pH, d, e)) + bf2f(ld_h(pL, d, e));
    const float v = 1.5f*pv - 0.5f*acc[i][j][r];
    const unsigned short h = f2bf(v);
    st_h(dH, d, e, h);
    st_h(dL, d, e, f2bf(v - bf2f(h)));
  }
}

__global__ __launch_bounds__(256) void k_ns(const float* __restrict__ S1,
                                            const float* __restrict__ S2,
                                            const float* __restrict__ weight,
                                            const float* __restrict__ bias,
                                            float* __restrict__ wm,
                                            float* __restrict__ beta){
  __shared__ __align__(16) unsigned short smem[8*4096];   // 64 KiB exactly
  unsigned short* Snh = smem;
  unsigned short* Snl = smem + 1*4096;
  unsigned short* Xh  = smem + 2*4096;
  unsigned short* Xl  = smem + 3*4096;
  unsigned short* Yh  = smem + 4*4096;
  unsigned short* Yl  = smem + 5*4096;
  unsigned short* Zh  = smem + 6*4096;
  unsigned short* Zl  = smem + 7*4096;
  const int g = blockIdx.x, tid = threadIdx.x;
  const int lane = tid & 63, wave = tid >> 6;
  const float* S1g = S1 + g*NC_;
  const float* S2g = S2 + g*NC_*NC_;
  const float invm = 1.0f / (float)M_;

  // trace of Sigma: lane-parallel (1 diag elem / lane) + butterfly reduce
  float term;
  {
    const float mui = S1g[lane] * invm;
    term = S2g[lane*NC_ + lane]*invm - mui*mui + EPS_;
    #pragma unroll
    for(int m2 = 1; m2 < 64; m2 <<= 1) term += __shfl_xor(term, m2, 64);
  }
  const float rTr  = 1.0f / term;
  const float srtr = sqrtf(rTr);

  {
    const int d  = tid >> 2;
    const int e0 = (tid & 3) * 16;
    const float mud = S1g[d] * invm;
    for(int k = 0; k < 16; ++k){
      const int e = e0 + k;
      const float mue = S1g[e] * invm;
      const float s = (S2g[d*NC_ + e]*invm - mud*mue + ((d==e)?EPS_:0.f)) * rTr;
      const unsigned short h = f2bf(s);
      st_h(Snh, d, e, h);
      st_h(Snl, d, e, f2bf(s - bf2f(h)));
      st_h(Xh,  d, e, (d==e)?(unsigned short)0x3F80:(unsigned short)0);
      st_h(Xl,  d, e, (unsigned short)0);
    }
  }
  wg_barrier();

  unsigned short *pH = Xh, *pL = Xl, *qH = Yh, *qL = Yl;
  const int wrow = (wave >> 1)*32, wcol = (wave & 1)*32;
  for(int it = 0; it < TIT_; ++it){
    mm64(qH, qL, pH, pL, pH, pL, lane, wrow, wcol);     // T1 = P*P
    wg_barrier();
    mm64(Zh, Zl, qH, qL, pH, pL, lane, wrow, wcol);     // T2 = T1*P
    wg_barrier();
    ns_update(qH, qL, Zh, Zl, Snh, Snl, pH, pL, lane, wrow, wcol); // P' into q
    wg_barrier();
    unsigned short* t;
    t = pH; pH = qH; qH = t;
    t = pL; pL = qL; qL = t;
  }

  // wm' = P*sqrt(rTr)*w[d]; beta = bias - wm'@mu  (weight folded into wm)
  float* wmg = wm + g*NC_*NC_;
  const int d  = tid >> 2;
  const int e0 = (tid & 3) * 16;
  const float wd = weight[g*NC_ + d] * srtr;
  float rs = 0.f;
  for(int k = 0; k < 16; ++k){
    const int e = e0 + k;
    const float wv = (bf2f(ld_h(pH, d, e)) + bf2f(ld_h(pL, d, e))) * wd;
    wmg[d*NC_ + e] = wv;
    rs += wv * (S1g[e] * invm);
  }
  rs += __shfl_xor(rs, 1, 64);
  rs += __shfl_xor(rs, 2, 64);
  if((tid & 3) == 0)
    beta[g*NC_ + d] = bias[g*NC_ + d] - rs;
}

// ---------------- Pass 3: apply ----------------
__global__ __launch_bounds__(256) void k_apply(const float* __restrict__ x,
                                               const float* __restrict__ wm,
                                               const float* __restrict__ beta,
                                               float* __restrict__ out){
  // transposed tile: [pos][ch], rows 128B, byte ^= (pos&7)<<4
  __shared__ __align__(16) unsigned short tileT[2][64*64];
  const int tid  = threadIdx.x;
  const int lane = tid & 63, wave = tid >> 6;
  const int bx   = blockIdx.x;
  const int g = bx >> 7, sub = bx & 127, b = sub >> 1, half = sub & 1;
  const int ck0 = half ? 24 : 0, ck1 = half ? 49 : 24;
  const int nck = ck1 - ck0;
  const float* xg = x   + ((size_t)b*C_ + (size_t)g*NC_) * HW_;
  float*       og = out + ((size_t)b*C_ + (size_t)g*NC_) * HW_;
  const int chb = (tid >> 4) * 4;
  const int posoff = (tid & 15) * 4;

  // wm' fragments (hi/lo) in registers; wm' symmetric-scaled, B operand.
  const float* wmg = wm + g*NC_*NC_;
  const int arow = wave*16 + (lane & 15);   // this lane's output channel
  s16x8 ah[2], al[2];
  #pragma unroll
  for(int ks = 0; ks < 2; ++ks){
    const int kc = ks*32 + (lane >> 4)*8;
    const float* p = wmg + arow*NC_ + kc;
    #pragma unroll
    for(int j = 0; j < 8; ++j){
      const float w = p[j];
      const unsigned short h = f2bf(w);
      ah[ks][j] = (short)h;
      al[ks][j] = (short)f2bf(w - bf2f(h));
    }
  }
  const int cl = wave*16 + (lane & 15);     // output channel (local)
  const float bt = beta[g*NC_ + cl];

  float v[4][4];
  auto load_c = [&](int ck){
    #pragma unroll
    for(int q = 0; q < 4; ++q){
      const float4 t = *(const float4*)(xg + (size_t)(chb+q)*HW_ + ck*64 + posoff);
      v[q][0]=t.x; v[q][1]=t.y; v[q][2]=t.z; v[q][3]=t.w;
    }
  };
  auto write_c = [&](unsigned short* tl){
    #pragma unroll
    for(int r = 0; r < 4; ++r){
      const int p = posoff + r;
      const unsigned long long pk =
            (unsigned long long)f2bf(v[0][r])
          | ((unsigned long long)f2bf(v[1][r]) << 16)
          | ((unsigned long long)f2bf(v[2][r]) << 32)
          | ((unsigned long long)f2bf(v[3][r]) << 48);
      *(unsigned long long*)((char*)tl + p*128 + ((chb*2) ^ ((p & 7) << 4))) = pk;
    }
  };
  auto comp = [&](const unsigned short* tl, int p0){
    #pragma unroll
    for(int tn = 0; tn < 4; ++tn){
      f32x4 acc = {0.f,0.f,0.f,0.f};
      const int pos = tn*16 + (lane & 15);   // A row = position
      #pragma unroll
      for(int ks = 0; ks < 2; ++ks){
        const int cb = (ks*64 + (lane >> 4)*16) ^ ((pos & 7) << 4);
        const s16x8 afr = *(const s16x8*)((const char*)tl + pos*128 + cb);
        MFMA_(afr, ah[ks], acc);             // D[pos][ch_out]
        MFMA_(afr, al[ks], acc);
      }
      const int pr = p0 + tn*16 + ((lane >> 4) << 2);  // 4 consecutive positions
      f32x4 o;
      o[0] = acc[0] + bt;
      o[1] = acc[1] + bt;
      o[2] = acc[2] + bt;
      o[3] = acc[3] + bt;
      __builtin_nontemporal_store(o, (f32x4*)(og + (size_t)cl*HW_ + pr));
    }
  };

  // distance-2 prefetch, 2 LDS buffers; raw barrier keeps loads/stores in flight
  load_c(ck0);
  write_c(tileT[0]);
  if(nck > 1) load_c(ck0 + 1);
  wg_barrier();
  for(int i = 0; i < nck; ++i){
    if(i + 1 < nck) write_c(tileT[(i+1)&1]);
    if(i + 2 < nck) load_c(ck0 + i + 2);
    comp(tileT[i&1], (ck0 + i)*64);
    wg_barrier();
  }
}

extern "C" void kernel_launch(void* const* d_in, const int* in_sizes, int n_in,
                              void* d_out, int out_size, void* d_ws, size_t ws_size,
                              hipStream_t stream){
  (void)in_sizes; (void)n_in; (void)out_size;
  const float* x  = (const float*)d_in[0];
  const float* w  = (const float*)d_in[1];
  const float* bs = (const float*)d_in[2];
  float* out  = (float*)d_out;
  float* S1   = (float*)d_ws;                // 256
  float* S2   = S1 + 256;                    // 4*4096
  float* beta = S2 + G_*NC_*NC_;             // 256
  float* wm   = beta + 256;                  // 4*4096
  float* p2   = wm + G_*NC_*NC_;             // NGB_*4096
  float* p1   = p2 + (size_t)NGB_*4096;      // NGB_*64
  const size_t need = ((size_t)(256 + G_*4096 + 256 + G_*4096)
                       + (size_t)NGB_*4096 + (size_t)NGB_*64) * sizeof(float);
  if(ws_size >= need){
    k_gram<false><<<NGB_, 256, 0, stream>>>(x, S1, S2, p2, p1);
    k_reduce<<<260, 256, 0, stream>>>(p2, p1, S1, S2);
  }else{
    hipError_t _e = hipMemsetAsync(d_ws, 0, (256 + G_*NC_*NC_)*sizeof(float), stream);
    (void)_e;
    k_gram<true><<<NGB_, 256, 0, stream>>>(x, S1, S2, p2, p1);
  }
  k_ns   <<<G_,   256, 0, stream>>>(S1, S2, w, bs, wm, beta);
  k_apply<<<512,  256, 0, stream>>>(x, wm, beta, out);
}